// Round 1
// 380.841 us; speedup vs baseline: 1.0227x; 1.0227x over previous
//
#include <hip/hip_runtime.h>

#define HDIM 1024
#define NR 6   // effective output rows: 2 joint + 2 (group 0) + 2 (group 1)

// ---------------------------------------------------------------------------
// Kernel 1: A[6][H] = W2 @ W_phi  (W2 rows = [W_joint(2); W_groups(4)])
// blocks 0..127: block cb owns 8 columns, 32 k-slices of 32 h each,
// LDS-reduced -> direct store (no atomics, no zero-init needed).
// block 128: bias_eff[r] = W2[r,:]·b_phi + b2[r]  (wave-parallel butterfly)
// ---------------------------------------------------------------------------
__global__ __launch_bounds__(256) void precompute_kernel(
    const float* __restrict__ Wphi, const float* __restrict__ bphi,
    const float* __restrict__ Wg,  const float* __restrict__ bg,
    const float* __restrict__ Wj,  const float* __restrict__ bj,
    float* __restrict__ A, float* __restrict__ biasEff)
{
    const int t = threadIdx.x;

    if (blockIdx.x == 128) {
        // bias block: wave w handles rows w and w+4 (rows 0..5)
        const int lane = t & 63;
        const int w    = t >> 6;
        for (int r = w; r < NR; r += 4) {
            const float* w2 = (r < 2) ? (Wj + (size_t)r * HDIM)
                                      : (Wg + (size_t)(r - 2) * HDIM);
            const float4* w4 = (const float4*)w2;
            const float4* p4 = (const float4*)bphi;
            float s = 0.f;
            #pragma unroll
            for (int j = 0; j < 4; ++j) {
                const float4 av = w4[lane + 64 * j];
                const float4 bv = p4[lane + 64 * j];
                s += av.x * bv.x + av.y * bv.y + av.z * bv.z + av.w * bv.w;
            }
            #pragma unroll
            for (int off = 32; off > 0; off >>= 1)
                s += __shfl_xor(s, off, 64);
            if (lane == 0)
                biasEff[r] = s + ((r < 2) ? bj[r] : bg[r - 2]);
        }
        return;
    }

    const int cb  = blockIdx.x;        // 0..127, 8 columns per block
    const int col = cb * 8 + (t & 7);
    const int ks  = t >> 3;            // 32 k-slices of 32 h each
    const int h0  = ks * 32;

    float acc[NR];
    #pragma unroll
    for (int r = 0; r < NR; ++r) acc[r] = 0.f;

    #pragma unroll 8
    for (int i = 0; i < 32; ++i) {
        const int h = h0 + i;
        const float wv = Wphi[(size_t)h * HDIM + col];
        acc[0] += Wj[h]            * wv;
        acc[1] += Wj[HDIM + h]     * wv;
        acc[2] += Wg[h]            * wv;
        acc[3] += Wg[HDIM + h]     * wv;
        acc[4] += Wg[2 * HDIM + h] * wv;
        acc[5] += Wg[3 * HDIM + h] * wv;
    }

    __shared__ float red[256][NR];
    #pragma unroll
    for (int r = 0; r < NR; ++r) red[t][r] = acc[r];
    __syncthreads();

    if (t < 8 * NR) {
        const int c = t & 7;
        const int r = t >> 3;          // 0..5
        float s = 0.f;
        #pragma unroll
        for (int k = 0; k < 32; ++k) s += red[k * 8 + c][r];
        A[(size_t)r * HDIM + cb * 8 + c] = s;
    }
}

// ---------------------------------------------------------------------------
// Kernel 2: Y[b,0:6] = X[b,:] @ A.T + bias_eff; gather by D / D_agn; write
//   out[0    .. 2B) = joint (rows 0,1)
//   out[2B   .. 4B) = group_specific (rows 2+2*D[b]+c)
//   out[4B   .. 6B) = group_agnostic (rows 2+2*Dagn[b]+c)
// One wave per row; A held in registers (96 VGPRs); 64-lane butterfly reduce.
// grid=768 blocks -> 3072 waves = exactly resident at 3 blocks/CU, no tail.
// v2: manual 2x-unrolled loop with ping-pong x0/x1 register prefetch so the
// next sample's 4 KB of X is in flight during the current sample's
// dot-product + butterfly + store tail. D/Dagn loads hoisted above reduce.
// ---------------------------------------------------------------------------
__global__ __launch_bounds__(256, 3) void main_kernel(
    const float* __restrict__ X, const int* __restrict__ D,
    const int* __restrict__ Dagn,
    const float* __restrict__ A, const float* __restrict__ biasEff,
    float* __restrict__ out, int B)
{
    const int lane  = threadIdx.x & 63;
    const int wave  = threadIdx.x >> 6;
    const int gwave = blockIdx.x * 4 + wave;
    const int nwav  = gridDim.x * 4;

    // A fragments in registers: 6 rows x 4 float4 = 96 VGPRs
    float4 a[NR][4];
    #pragma unroll
    for (int r = 0; r < NR; ++r) {
        const float4* Ar = (const float4*)(A + (size_t)r * HDIM);
        #pragma unroll
        for (int j = 0; j < 4; ++j) a[r][j] = Ar[lane + 64 * j];
    }
    float be[NR];
    #pragma unroll
    for (int r = 0; r < NR; ++r) be[r] = biasEff[r];

    if (gwave >= B) return;

    float4 x0[4], x1[4];
    {
        const float4* xr = (const float4*)(X + (size_t)gwave * HDIM);
        #pragma unroll
        for (int j = 0; j < 4; ++j) x0[j] = xr[lane + 64 * j];
    }

#define PROCESS(bb, xx)                                                     \
    {                                                                       \
        const int d_  = D[bb] & 1;     /* uniform broadcast load, issued */ \
        const int da_ = Dagn[bb] & 1;  /* before the reduce tail        */  \
        float acc[NR];                                                      \
        _Pragma("unroll")                                                   \
        for (int r = 0; r < NR; ++r) {                                      \
            float s = 0.f;                                                  \
            _Pragma("unroll")                                               \
            for (int j = 0; j < 4; ++j)                                     \
                s += xx[j].x * a[r][j].x + xx[j].y * a[r][j].y              \
                   + xx[j].z * a[r][j].z + xx[j].w * a[r][j].w;             \
            acc[r] = s;                                                     \
        }                                                                   \
        _Pragma("unroll")                                                   \
        for (int r = 0; r < NR; ++r) {                                      \
            float v = acc[r];                                               \
            _Pragma("unroll")                                               \
            for (int off = 32; off > 0; off >>= 1)                          \
                v += __shfl_xor(v, off, 64);                                \
            acc[r] = v;                                                     \
        }                                                                   \
        if (lane == 0) {                                                    \
            float2* o = (float2*)out;                                       \
            o[bb]         = make_float2(acc[0] + be[0], acc[1] + be[1]);    \
            o[B + bb]     = make_float2(acc[2 + 2 * d_]  + be[2 + 2 * d_],  \
                                        acc[3 + 2 * d_]  + be[3 + 2 * d_]); \
            o[2 * B + bb] = make_float2(acc[2 + 2 * da_] + be[2 + 2 * da_], \
                                        acc[3 + 2 * da_] + be[3 + 2 * da_]);\
        }                                                                   \
    }

    int b = gwave;
    while (true) {
        const int b1 = b + nwav;
        if (b1 < B) {
            const float4* xr = (const float4*)(X + (size_t)b1 * HDIM);
            #pragma unroll
            for (int j = 0; j < 4; ++j) x1[j] = xr[lane + 64 * j];
        }
        PROCESS(b, x0)
        if (b1 >= B) break;

        const int b2 = b1 + nwav;
        if (b2 < B) {
            const float4* xr = (const float4*)(X + (size_t)b2 * HDIM);
            #pragma unroll
            for (int j = 0; j < 4; ++j) x0[j] = xr[lane + 64 * j];
        }
        PROCESS(b1, x1)
        if (b2 >= B) break;
        b = b2;
    }
#undef PROCESS
}

extern "C" void kernel_launch(void* const* d_in, const int* in_sizes, int n_in,
                              void* d_out, int out_size, void* d_ws, size_t ws_size,
                              hipStream_t stream) {
    const float* X    = (const float*)d_in[0];
    const float* Wphi = (const float*)d_in[1];
    const float* bphi = (const float*)d_in[2];
    const float* Wg   = (const float*)d_in[3];
    const float* bg   = (const float*)d_in[4];
    const float* Wj   = (const float*)d_in[5];
    const float* bj   = (const float*)d_in[6];
    const int*   D    = (const int*)d_in[7];
    const int*   Dagn = (const int*)d_in[8];
    float* out = (float*)d_out;

    const int B = in_sizes[7];  // 65536

    float* A       = (float*)d_ws;          // 6*1024 floats (fully overwritten)
    float* biasEff = A + NR * HDIM;         // 6 floats (fully overwritten)

    precompute_kernel<<<129, 256, 0, stream>>>(Wphi, bphi, Wg, bg, Wj, bj, A, biasEff);
    main_kernel<<<768, 256, 0, stream>>>(X, D, Dagn, A, biasEff, out, B);
}

// Round 4
// 362.931 us; speedup vs baseline: 1.0731x; 1.0494x over previous
//
#include <hip/hip_runtime.h>

#define HDIM 1024
#define NR 6   // effective output rows: 2 joint + 2 (group 0) + 2 (group 1)

typedef float f4 __attribute__((ext_vector_type(4)));  // native vec4 (NT-load-compatible)

// ---------------------------------------------------------------------------
// Kernel 1: A[6][H] = W2 @ W_phi  (W2 rows = [W_joint(2); W_groups(4)])
// blocks 0..127: block cb owns 8 columns, 32 k-slices of 32 h each,
// LDS-reduced -> direct store (no atomics, no zero-init needed).
// block 128: bias_eff[r] = W2[r,:]·b_phi + b2[r]  (wave-parallel butterfly)
// ---------------------------------------------------------------------------
__global__ __launch_bounds__(256) void precompute_kernel(
    const float* __restrict__ Wphi, const float* __restrict__ bphi,
    const float* __restrict__ Wg,  const float* __restrict__ bg,
    const float* __restrict__ Wj,  const float* __restrict__ bj,
    float* __restrict__ A, float* __restrict__ biasEff)
{
    const int t = threadIdx.x;

    if (blockIdx.x == 128) {
        // bias block: wave w handles rows w and w+4 (rows 0..5)
        const int lane = t & 63;
        const int w    = t >> 6;
        for (int r = w; r < NR; r += 4) {
            const float* w2 = (r < 2) ? (Wj + (size_t)r * HDIM)
                                      : (Wg + (size_t)(r - 2) * HDIM);
            const f4* w4 = (const f4*)w2;
            const f4* p4 = (const f4*)bphi;
            float s = 0.f;
            #pragma unroll
            for (int j = 0; j < 4; ++j) {
                const f4 av = w4[lane + 64 * j];
                const f4 bv = p4[lane + 64 * j];
                s += av[0] * bv[0] + av[1] * bv[1] + av[2] * bv[2] + av[3] * bv[3];
            }
            #pragma unroll
            for (int off = 32; off > 0; off >>= 1)
                s += __shfl_xor(s, off, 64);
            if (lane == 0)
                biasEff[r] = s + ((r < 2) ? bj[r] : bg[r - 2]);
        }
        return;
    }

    const int cb  = blockIdx.x;        // 0..127, 8 columns per block
    const int col = cb * 8 + (t & 7);
    const int ks  = t >> 3;            // 32 k-slices of 32 h each
    const int h0  = ks * 32;

    float acc[NR];
    #pragma unroll
    for (int r = 0; r < NR; ++r) acc[r] = 0.f;

    #pragma unroll 8
    for (int i = 0; i < 32; ++i) {
        const int h = h0 + i;
        const float wv = Wphi[(size_t)h * HDIM + col];
        acc[0] += Wj[h]            * wv;
        acc[1] += Wj[HDIM + h]     * wv;
        acc[2] += Wg[h]            * wv;
        acc[3] += Wg[HDIM + h]     * wv;
        acc[4] += Wg[2 * HDIM + h] * wv;
        acc[5] += Wg[3 * HDIM + h] * wv;
    }

    __shared__ float red[256][NR];
    #pragma unroll
    for (int r = 0; r < NR; ++r) red[t][r] = acc[r];
    __syncthreads();

    if (t < 8 * NR) {
        const int c = t & 7;
        const int r = t >> 3;          // 0..5
        float s = 0.f;
        #pragma unroll
        for (int k = 0; k < 32; ++k) s += red[k * 8 + c][r];
        A[(size_t)r * HDIM + cb * 8 + c] = s;
    }
}

// ---------------------------------------------------------------------------
// Kernel 2: Y[b,0:6] = X[b,:] @ A.T + bias_eff; gather by D / D_agn; write
//   out[0    .. 2B) = joint (rows 0,1)
//   out[2B   .. 4B) = group_specific (rows 2+2*D[b]+c)
//   out[4B   .. 6B) = group_agnostic (rows 2+2*Dagn[b]+c)
// One wave per row; A held in registers (96 VGPRs); 64-lane butterfly reduce.
// grid=768 blocks -> 3072 waves = exactly resident at 3 blocks/CU, no tail.
// v3: ping-pong x0/x1 register prefetch (verified R1 structure) + nontemporal
// X loads — X is 256 MB streamed exactly once; NT skips LLC allocation so the
// stream doesn't fight the harness fill/output traffic for L3 residency.
// ---------------------------------------------------------------------------
__global__ __launch_bounds__(256, 3) void main_kernel(
    const float* __restrict__ X, const int* __restrict__ D,
    const int* __restrict__ Dagn,
    const float* __restrict__ A, const float* __restrict__ biasEff,
    float* __restrict__ out, int B)
{
    const int lane  = threadIdx.x & 63;
    const int wave  = threadIdx.x >> 6;
    const int gwave = blockIdx.x * 4 + wave;
    const int nwav  = gridDim.x * 4;

    // A fragments in registers: 6 rows x 4 f4 = 96 VGPRs
    f4 a[NR][4];
    #pragma unroll
    for (int r = 0; r < NR; ++r) {
        const f4* Ar = (const f4*)(A + (size_t)r * HDIM);
        #pragma unroll
        for (int j = 0; j < 4; ++j) a[r][j] = Ar[lane + 64 * j];
    }
    float be[NR];
    #pragma unroll
    for (int r = 0; r < NR; ++r) be[r] = biasEff[r];

    if (gwave >= B) return;

    f4 x0[4], x1[4];
    {
        const f4* xr = (const f4*)(X + (size_t)gwave * HDIM);
        #pragma unroll
        for (int j = 0; j < 4; ++j) x0[j] = __builtin_nontemporal_load(&xr[lane + 64 * j]);
    }

#define PROCESS(bb, xx)                                                     \
    {                                                                       \
        const int d_  = D[bb] & 1;     /* uniform broadcast load, issued */ \
        const int da_ = Dagn[bb] & 1;  /* before the reduce tail        */  \
        float acc[NR];                                                      \
        _Pragma("unroll")                                                   \
        for (int r = 0; r < NR; ++r) {                                      \
            float s = 0.f;                                                  \
            _Pragma("unroll")                                               \
            for (int j = 0; j < 4; ++j)                                     \
                s += xx[j][0] * a[r][j][0] + xx[j][1] * a[r][j][1]          \
                   + xx[j][2] * a[r][j][2] + xx[j][3] * a[r][j][3];         \
            acc[r] = s;                                                     \
        }                                                                   \
        _Pragma("unroll")                                                   \
        for (int r = 0; r < NR; ++r) {                                      \
            float v = acc[r];                                               \
            _Pragma("unroll")                                               \
            for (int off = 32; off > 0; off >>= 1)                          \
                v += __shfl_xor(v, off, 64);                                \
            acc[r] = v;                                                     \
        }                                                                   \
        if (lane == 0) {                                                    \
            float2* o = (float2*)out;                                       \
            o[bb]         = make_float2(acc[0] + be[0], acc[1] + be[1]);    \
            o[B + bb]     = make_float2(acc[2 + 2 * d_]  + be[2 + 2 * d_],  \
                                        acc[3 + 2 * d_]  + be[3 + 2 * d_]); \
            o[2 * B + bb] = make_float2(acc[2 + 2 * da_] + be[2 + 2 * da_], \
                                        acc[3 + 2 * da_] + be[3 + 2 * da_]);\
        }                                                                   \
    }

    int b = gwave;
    while (true) {
        const int b1 = b + nwav;
        if (b1 < B) {
            const f4* xr = (const f4*)(X + (size_t)b1 * HDIM);
            #pragma unroll
            for (int j = 0; j < 4; ++j) x1[j] = __builtin_nontemporal_load(&xr[lane + 64 * j]);
        }
        PROCESS(b, x0)
        if (b1 >= B) break;

        const int b2 = b1 + nwav;
        if (b2 < B) {
            const f4* xr = (const f4*)(X + (size_t)b2 * HDIM);
            #pragma unroll
            for (int j = 0; j < 4; ++j) x0[j] = __builtin_nontemporal_load(&xr[lane + 64 * j]);
        }
        PROCESS(b1, x1)
        if (b2 >= B) break;
        b = b2;
    }
#undef PROCESS
}

extern "C" void kernel_launch(void* const* d_in, const int* in_sizes, int n_in,
                              void* d_out, int out_size, void* d_ws, size_t ws_size,
                              hipStream_t stream) {
    const float* X    = (const float*)d_in[0];
    const float* Wphi = (const float*)d_in[1];
    const float* bphi = (const float*)d_in[2];
    const float* Wg   = (const float*)d_in[3];
    const float* bg   = (const float*)d_in[4];
    const float* Wj   = (const float*)d_in[5];
    const float* bj   = (const float*)d_in[6];
    const int*   D    = (const int*)d_in[7];
    const int*   Dagn = (const int*)d_in[8];
    float* out = (float*)d_out;

    const int B = in_sizes[7];  // 65536

    float* A       = (float*)d_ws;          // 6*1024 floats (fully overwritten)
    float* biasEff = A + NR * HDIM;         // 6 floats (fully overwritten)

    precompute_kernel<<<129, 256, 0, stream>>>(Wphi, bphi, Wg, bg, Wj, bj, A, biasEff);
    main_kernel<<<768, 256, 0, stream>>>(X, D, Dagn, A, biasEff, out, B);
}